// Round 8
// baseline (344.703 us; speedup 1.0000x reference)
//
#include <hip/hip_runtime.h>

constexpr int SEQ = 2048;
constexpr int DM = 1024;
constexpr int NH = 16;
constexpr int BATCH = 2;
constexpr int MTOT = BATCH * SEQ;   // 4096

typedef __bf16 bf16x8 __attribute__((ext_vector_type(8)));
typedef float f32x4 __attribute__((ext_vector_type(4)));

#define MFMA16(a, b, c) __builtin_amdgcn_mfma_f32_16x16x32_bf16((a), (b), (c), 0, 0, 0)

__global__ void sentinel_fill(float* out, int n) {
  int i = blockIdx.x * blockDim.x + threadIdx.x;
  for (; i < n; i += gridDim.x * blockDim.x) out[i] = 0.25f;
}

template <int F32>
__device__ __forceinline__ bf16x8 load_cvt8(const void* base, long off) {
  if constexpr (F32) {
    const float* p = (const float*)base + off;
    f32x4 lo = *(const f32x4*)p;
    f32x4 hi = *(const f32x4*)(p + 4);
    bf16x8 r;
#pragma unroll
    for (int j = 0; j < 4; ++j) { r[j] = (__bf16)lo[j]; r[4 + j] = (__bf16)hi[j]; }
    return r;
  } else {
    return *(const bf16x8*)((const __bf16*)base + off);
  }
}

// C[M,N] = A[M,K] * B[N,K]^T.  OutT selects the C dtype: bf16 for the qkv
// scratch (gemm1), FLOAT for the final output — d_out is FP32 per the
// reference's output dtype (R5-R7 failures were bf16 writes into an fp32
// buffer: half-filled buffer + garbled words -> deterministic absmax 3.13).
template <int AF32, int BF32, typename OutT>
__global__ __launch_bounds__(256) void gemm_nt(const void* __restrict__ Av,
                                               const void* __restrict__ Bv,
                                               OutT* __restrict__ C,
                                               int M, int N, int K, int lda,
                                               float nanSig) {
  __shared__ alignas(16) __bf16 As[128 * 32];
  __shared__ alignas(16) __bf16 Bs[128 * 32];
  const int tid = threadIdx.x;
  const int lane = tid & 63;
  const int wave = tid >> 6;
  const int lr = lane & 15;
  const int quad = lane >> 4;
  const int wm = (wave >> 1) * 64;
  const int wn = (wave & 1) * 64;
  const int m0 = blockIdx.y * 128;
  const int n0 = blockIdx.x * 128;

  const int r0 = tid >> 2;
  const int r1 = 64 + (tid >> 2);
  const int cc = (tid & 3) * 8;
  const long aBase0 = (long)(m0 + r0) * lda + cc;
  const long aBase1 = (long)(m0 + r1) * lda + cc;
  const long bBase0 = (long)(n0 + r0) * K + cc;
  const long bBase1 = (long)(n0 + r1) * K + cc;
  __bf16* lA0 = &As[r0 * 32 + cc];
  __bf16* lA1 = &As[r1 * 32 + cc];
  __bf16* lB0 = &Bs[r0 * 32 + cc];
  __bf16* lB1 = &Bs[r1 * 32 + cc];

  f32x4 acc[4][4];
#pragma unroll
  for (int i = 0; i < 4; ++i)
#pragma unroll
    for (int j = 0; j < 4; ++j) acc[i][j] = (f32x4){0.f, 0.f, 0.f, 0.f};

  for (int k0 = 0; k0 < K; k0 += 32) {
    bf16x8 va0 = load_cvt8<AF32>(Av, aBase0 + k0);
    bf16x8 va1 = load_cvt8<AF32>(Av, aBase1 + k0);
    bf16x8 vb0 = load_cvt8<BF32>(Bv, bBase0 + k0);
    bf16x8 vb1 = load_cvt8<BF32>(Bv, bBase1 + k0);
    __syncthreads();
    *(bf16x8*)lA0 = va0;
    *(bf16x8*)lA1 = va1;
    *(bf16x8*)lB0 = vb0;
    *(bf16x8*)lB1 = vb1;
    __syncthreads();
    bf16x8 af[4], bfr[4];
#pragma unroll
    for (int i = 0; i < 4; ++i) af[i] = *(const bf16x8*)&As[(wm + i * 16 + lr) * 32 + quad * 8];
#pragma unroll
    for (int j = 0; j < 4; ++j) bfr[j] = *(const bf16x8*)&Bs[(wn + j * 16 + lr) * 32 + quad * 8];
#pragma unroll
    for (int i = 0; i < 4; ++i)
#pragma unroll
      for (int j = 0; j < 4; ++j) acc[i][j] = MFMA16(af[i], bfr[j], acc[i][j]);
  }

#pragma unroll
  for (int i = 0; i < 4; ++i) {
    const int row = m0 + wm + i * 16 + quad * 4;
#pragma unroll
    for (int j = 0; j < 4; ++j) {
      const int col = n0 + wn + j * 16 + lr;
#pragma unroll
      for (int r = 0; r < 4; ++r) {
        float v = acc[i][j][r];
        if (!(v == v)) v = nanSig;
        C[(long)(row + r) * N + col] = (OutT)v;
      }
    }
  }
}

// Flash causal attention, in-place into the q-slice of qkv (bf16 scratch).
__global__ __launch_bounds__(256) void attn_fwd(__bf16* __restrict__ qkv) {
  const int qt = gridDim.x - 1 - blockIdx.x;
  const int h = blockIdx.y;
  const int b = blockIdx.z;
  const int q0 = qt * 128;
  const int tid = threadIdx.x;
  const int lane = tid & 63;
  const int wave = tid >> 6;
  const int lr = lane & 15;
  const int quad = lane >> 4;

  __shared__ alignas(16) __bf16 Ks[64 * 72];
  __shared__ alignas(16) __bf16 Vt[64 * 72];
  __shared__ alignas(16) __bf16 Ps[128 * 72];

  const long base = (long)b * SEQ * 3072;

  bf16x8 a_q[2][2];
#pragma unroll
  for (int mi = 0; mi < 2; ++mi) {
    const long rowoff = base + (long)(q0 + wave * 32 + mi * 16 + lr) * 3072 + h * 64;
#pragma unroll
    for (int ks = 0; ks < 2; ++ks)
      a_q[mi][ks] = *(const bf16x8*)(qkv + rowoff + ks * 32 + quad * 8);
  }

  const float NEG = -30000.f;
  float m_i[2][4], l_i[2][4], alpha[2][4];
  f32x4 o_acc[2][4];
#pragma unroll
  for (int mi = 0; mi < 2; ++mi)
#pragma unroll
    for (int r = 0; r < 4; ++r) { m_i[mi][r] = NEG; l_i[mi][r] = 0.f; }
#pragma unroll
  for (int mi = 0; mi < 2; ++mi)
#pragma unroll
    for (int dt = 0; dt < 4; ++dt) o_acc[mi][dt] = (f32x4){0.f, 0.f, 0.f, 0.f};

  for (int kv0 = 0; kv0 < q0 + 128; kv0 += 64) {
    __syncthreads();
#pragma unroll
    for (int c = 0; c < 2; ++c) {
      const int e = tid * 8 + c * 2048;
      const int r = e >> 6, col = e & 63;
      bf16x8 v = *(const bf16x8*)(qkv + base + (long)(kv0 + r) * 3072 + 1024 + h * 64 + col);
      *(bf16x8*)&Ks[r * 72 + col] = v;
    }
#pragma unroll
    for (int c = 0; c < 16; ++c) {
      const int e = tid + c * 256;
      const int r = e >> 6, col = e & 63;
      Vt[col * 72 + r] = qkv[base + (long)(kv0 + r) * 3072 + 2048 + h * 64 + col];
    }
    __syncthreads();

    f32x4 s_acc[2][4];
#pragma unroll
    for (int mi = 0; mi < 2; ++mi)
#pragma unroll
      for (int ni = 0; ni < 4; ++ni) s_acc[mi][ni] = (f32x4){0.f, 0.f, 0.f, 0.f};
#pragma unroll
    for (int ks = 0; ks < 2; ++ks) {
      bf16x8 bk[4];
#pragma unroll
      for (int ni = 0; ni < 4; ++ni)
        bk[ni] = *(const bf16x8*)&Ks[(ni * 16 + lr) * 72 + ks * 32 + quad * 8];
#pragma unroll
      for (int mi = 0; mi < 2; ++mi)
#pragma unroll
        for (int ni = 0; ni < 4; ++ni) s_acc[mi][ni] = MFMA16(a_q[mi][ks], bk[ni], s_acc[mi][ni]);
    }

#pragma unroll
    for (int mi = 0; mi < 2; ++mi) {
      const int rbase = q0 + wave * 32 + mi * 16 + quad * 4;
#pragma unroll
      for (int r = 0; r < 4; ++r) {
        const int row = rbase + r;
        float vals[4];
        float mx = NEG;
#pragma unroll
        for (int ni = 0; ni < 4; ++ni) {
          const int col = kv0 + ni * 16 + lr;
          float s = s_acc[mi][ni][r] * 0.125f;
          s = (col <= row) ? s : NEG;
          vals[ni] = s;
          mx = fmaxf(mx, s);
        }
        mx = fmaxf(mx, __shfl_xor(mx, 1));
        mx = fmaxf(mx, __shfl_xor(mx, 2));
        mx = fmaxf(mx, __shfl_xor(mx, 4));
        mx = fmaxf(mx, __shfl_xor(mx, 8));
        const float mnew = fmaxf(m_i[mi][r], mx);
        const float a = __expf(m_i[mi][r] - mnew);
        float rs = 0.f;
#pragma unroll
        for (int ni = 0; ni < 4; ++ni) {
          const float p = __expf(vals[ni] - mnew);
          rs += p;
          s_acc[mi][ni][r] = p;
        }
        rs += __shfl_xor(rs, 1);
        rs += __shfl_xor(rs, 2);
        rs += __shfl_xor(rs, 4);
        rs += __shfl_xor(rs, 8);
        l_i[mi][r] = l_i[mi][r] * a + rs;
        m_i[mi][r] = mnew;
        alpha[mi][r] = a;
      }
    }

#pragma unroll
    for (int mi = 0; mi < 2; ++mi)
#pragma unroll
      for (int ni = 0; ni < 4; ++ni)
#pragma unroll
        for (int r = 0; r < 4; ++r)
          Ps[(wave * 32 + mi * 16 + quad * 4 + r) * 72 + ni * 16 + lr] = (__bf16)s_acc[mi][ni][r];

#pragma unroll
    for (int mi = 0; mi < 2; ++mi)
#pragma unroll
      for (int dt = 0; dt < 4; ++dt)
#pragma unroll
        for (int r = 0; r < 4; ++r) o_acc[mi][dt][r] *= alpha[mi][r];

    __syncthreads();

#pragma unroll
    for (int ks = 0; ks < 2; ++ks) {
      bf16x8 ap[2], bv[4];
#pragma unroll
      for (int mi = 0; mi < 2; ++mi)
        ap[mi] = *(const bf16x8*)&Ps[(wave * 32 + mi * 16 + lr) * 72 + ks * 32 + quad * 8];
#pragma unroll
      for (int dt = 0; dt < 4; ++dt)
        bv[dt] = *(const bf16x8*)&Vt[(dt * 16 + lr) * 72 + ks * 32 + quad * 8];
#pragma unroll
      for (int mi = 0; mi < 2; ++mi)
#pragma unroll
        for (int dt = 0; dt < 4; ++dt) o_acc[mi][dt] = MFMA16(ap[mi], bv[dt], o_acc[mi][dt]);
    }
  }

#pragma unroll
  for (int mi = 0; mi < 2; ++mi) {
#pragma unroll
    for (int r = 0; r < 4; ++r) {
      const float inv = 1.f / fmaxf(l_i[mi][r], 1e-30f);
      const int srow = q0 + wave * 32 + mi * 16 + quad * 4 + r;
      const long obase = base + (long)srow * 3072 + h * 64;
#pragma unroll
      for (int dt = 0; dt < 4; ++dt) {
        float v = o_acc[mi][dt][r] * inv;
        if (!(v == v)) v = 7.0f;
        qkv[obase + dt * 16 + lr] = (__bf16)v;
      }
    }
  }
}

// ============ sampled tripwires (kept one round; ~0 cost) ============
__global__ void init_flags(int* flags) {
  if (threadIdx.x < 3 && blockIdx.x == 0) flags[threadIdx.x] = 0;
}

__global__ __launch_bounds__(256) void verify_g1(const float* x, const float* w,
                                                 const __bf16* qkv, int* flags) {
  const int i = blockIdx.x;
  const int s = (i * 2731) & 4095;
  const int o = (int)(((long)i * 1217) % 3072);
  const int t = threadIdx.x;
  __shared__ float red[256];
  float sum = 0.f;
  for (int k = t * 4; k < t * 4 + 4; ++k)
    sum += (float)(__bf16)x[(long)s * DM + k] * (float)(__bf16)w[(long)o * DM + k];
  red[t] = sum; __syncthreads();
  for (int w2 = 128; w2 > 0; w2 >>= 1) { if (t < w2) red[t] += red[t + w2]; __syncthreads(); }
  if (t == 0) {
    float got = (float)qkv[(long)s * 3072 + o];
    if (fabsf(red[0] - got) > 0.05f) atomicAdd(flags + 0, 1);
  }
}

__global__ __launch_bounds__(256) void verify_g2(const __bf16* qkv, const float* w_o,
                                                 const float* out, int* flags) {
  const int i = blockIdx.x;
  const int s = (i * 2731) & 4095;
  const int o = (i * 733) & 1023;
  const int t = threadIdx.x;
  __shared__ float red[256];
  float sum = 0.f;
  for (int k = t * 4; k < t * 4 + 4; ++k)
    sum += (float)qkv[(long)s * 3072 + k] * (float)(__bf16)w_o[(long)o * DM + k];
  red[t] = sum; __syncthreads();
  for (int w2 = 128; w2 > 0; w2 >>= 1) { if (t < w2) red[t] += red[t + w2]; __syncthreads(); }
  if (t == 0) {
    float got = out[(long)s * DM + o];
    if (fabsf(red[0] - got) > 0.05f) atomicAdd(flags + 2, 1);
  }
}

__global__ void reporter(const int* flags, float* out) {
  if (threadIdx.x == 0 && blockIdx.x == 0) {
    int mask = (flags[0] ? 1 : 0) | (flags[1] ? 2 : 0) | (flags[2] ? 4 : 0);
    if (mask) out[0] = 100.f * (float)mask;
  }
}

extern "C" void kernel_launch(void* const* d_in, const int* in_sizes, int n_in,
                              void* d_out, int out_size, void* d_ws, size_t ws_size,
                              hipStream_t stream) {
  // remap inputs by unique sizes (insurance against ordering surprises)
  const float* x = (const float*)d_in[0];
  const float* w_qkv = (const float*)d_in[1];
  const float* w_o = (const float*)d_in[2];
  for (int i = 0; i < n_in; ++i) {
    if (in_sizes[i] == MTOT * DM) x = (const float*)d_in[i];
    else if (in_sizes[i] == 3 * DM * DM) w_qkv = (const float*)d_in[i];
    else if (in_sizes[i] == DM * DM) w_o = (const float*)d_in[i];
  }
  float* out = (float*)d_out;  // FP32 output per reference dtype

  const size_t qkvBytes = (size_t)MTOT * 3072 * 2;  // 24 MiB
  if (ws_size < qkvBytes + 4096) {
    sentinel_fill<<<256, 256, 0, stream>>>(out, out_size);
    return;
  }

  __bf16* qkv = (__bf16*)d_ws;
  int* flags = (int*)((char*)d_ws + qkvBytes);

  init_flags<<<1, 64, 0, stream>>>(flags);
  gemm_nt<1, 1, __bf16><<<dim3(3072 / 128, MTOT / 128), 256, 0, stream>>>(
      x, w_qkv, qkv, MTOT, 3072, DM, DM, 1e4f);
  verify_g1<<<512, 256, 0, stream>>>(x, w_qkv, qkv, flags);
  attn_fwd<<<dim3(SEQ / 128, NH, BATCH), 256, 0, stream>>>(qkv);
  gemm_nt<0, 1, float><<<dim3(DM / 128, MTOT / 128), 256, 0, stream>>>(
      qkv, w_o, out, MTOT, DM, DM, 3072, 2e4f);
  verify_g2<<<512, 256, 0, stream>>>(qkv, w_o, out, flags);
  reporter<<<1, 1, 0, stream>>>(flags, out);
}

// Round 9
// 273.661 us; speedup vs baseline: 1.2596x; 1.2596x over previous
//
#include <hip/hip_runtime.h>

constexpr int SEQ = 2048;
constexpr int DM = 1024;
constexpr int NH = 16;
constexpr int BATCH = 2;
constexpr int MTOT = BATCH * SEQ;   // 4096

typedef __bf16 bf16x8 __attribute__((ext_vector_type(8)));
typedef __bf16 bf16x4 __attribute__((ext_vector_type(4)));
typedef float f32x4 __attribute__((ext_vector_type(4)));

#define MFMA16(a, b, c) __builtin_amdgcn_mfma_f32_16x16x32_bf16((a), (b), (c), 0, 0, 0)

__global__ void sentinel_fill(float* out, int n) {
  int i = blockIdx.x * blockDim.x + threadIdx.x;
  for (; i < n; i += gridDim.x * blockDim.x) out[i] = 0.25f;
}

template <int F32>
__device__ __forceinline__ bf16x8 load_cvt8(const void* base, long off) {
  if constexpr (F32) {
    const float* p = (const float*)base + off;
    f32x4 lo = *(const f32x4*)p;
    f32x4 hi = *(const f32x4*)(p + 4);
    bf16x8 r;
#pragma unroll
    for (int j = 0; j < 4; ++j) { r[j] = (__bf16)lo[j]; r[4 + j] = (__bf16)hi[j]; }
    return r;
  } else {
    return *(const bf16x8*)((const __bf16*)base + off);
  }
}

// C[M,N] = A[M,K] * B[N,K]^T. 128x128 tile, BK=32, 4 waves (verified R8).
template <int AF32, int BF32, typename OutT>
__global__ __launch_bounds__(256) void gemm_nt(const void* __restrict__ Av,
                                               const void* __restrict__ Bv,
                                               OutT* __restrict__ C,
                                               int M, int N, int K, int lda,
                                               float nanSig) {
  __shared__ alignas(16) __bf16 As[128 * 32];
  __shared__ alignas(16) __bf16 Bs[128 * 32];
  const int tid = threadIdx.x;
  const int lane = tid & 63;
  const int wave = tid >> 6;
  const int lr = lane & 15;
  const int quad = lane >> 4;
  const int wm = (wave >> 1) * 64;
  const int wn = (wave & 1) * 64;
  const int m0 = blockIdx.y * 128;
  const int n0 = blockIdx.x * 128;

  const int r0 = tid >> 2;
  const int r1 = 64 + (tid >> 2);
  const int cc = (tid & 3) * 8;
  const long aBase0 = (long)(m0 + r0) * lda + cc;
  const long aBase1 = (long)(m0 + r1) * lda + cc;
  const long bBase0 = (long)(n0 + r0) * K + cc;
  const long bBase1 = (long)(n0 + r1) * K + cc;
  __bf16* lA0 = &As[r0 * 32 + cc];
  __bf16* lA1 = &As[r1 * 32 + cc];
  __bf16* lB0 = &Bs[r0 * 32 + cc];
  __bf16* lB1 = &Bs[r1 * 32 + cc];

  f32x4 acc[4][4];
#pragma unroll
  for (int i = 0; i < 4; ++i)
#pragma unroll
    for (int j = 0; j < 4; ++j) acc[i][j] = (f32x4){0.f, 0.f, 0.f, 0.f};

  for (int k0 = 0; k0 < K; k0 += 32) {
    bf16x8 va0 = load_cvt8<AF32>(Av, aBase0 + k0);
    bf16x8 va1 = load_cvt8<AF32>(Av, aBase1 + k0);
    bf16x8 vb0 = load_cvt8<BF32>(Bv, bBase0 + k0);
    bf16x8 vb1 = load_cvt8<BF32>(Bv, bBase1 + k0);
    __syncthreads();
    *(bf16x8*)lA0 = va0;
    *(bf16x8*)lA1 = va1;
    *(bf16x8*)lB0 = vb0;
    *(bf16x8*)lB1 = vb1;
    __syncthreads();
    bf16x8 af[4], bfr[4];
#pragma unroll
    for (int i = 0; i < 4; ++i) af[i] = *(const bf16x8*)&As[(wm + i * 16 + lr) * 32 + quad * 8];
#pragma unroll
    for (int j = 0; j < 4; ++j) bfr[j] = *(const bf16x8*)&Bs[(wn + j * 16 + lr) * 32 + quad * 8];
#pragma unroll
    for (int i = 0; i < 4; ++i)
#pragma unroll
      for (int j = 0; j < 4; ++j) acc[i][j] = MFMA16(af[i], bfr[j], acc[i][j]);
  }

#pragma unroll
  for (int i = 0; i < 4; ++i) {
    const int row = m0 + wm + i * 16 + quad * 4;
#pragma unroll
    for (int j = 0; j < 4; ++j) {
      const int col = n0 + wn + j * 16 + lr;
#pragma unroll
      for (int r = 0; r < 4; ++r) {
        float v = acc[i][j][r];
        if (!(v == v)) v = nanSig;
        C[(long)(row + r) * N + col] = (OutT)v;
      }
    }
  }
}

// Flash causal attention, S^T formulation (in-lane softmax reduction).
// Block = (b, h, 64 q-rows); 4 waves, each owning 16 q-rows; KV tile 64.
// In-place output into the q-slice of qkv (bf16 scratch).
__global__ __launch_bounds__(256, 4) void attn_fwd(__bf16* __restrict__ qkv) {
  const int qt = gridDim.x - 1 - blockIdx.x;  // big workloads first
  const int h = blockIdx.y;
  const int b = blockIdx.z;
  const int q0 = qt * 64;
  const int tid = threadIdx.x;
  const int lane = tid & 63;
  const int wave = tid >> 6;
  const int lr = lane & 15;
  const int quad = lane >> 4;

  __shared__ alignas(16) __bf16 Ks[64 * 72];      // K rows, [kv][d]
  __shared__ alignas(16) __bf16 Vt[64 * 72];      // V^T, [d][kv]
  __shared__ alignas(16) __bf16 Pq[4 * 16 * 72];  // per-wave P, [q][kv]

  __bf16* pqw = &Pq[wave * 16 * 72];
  const long base = (long)b * SEQ * 3072;
  const int qi = q0 + wave * 16 + lr;  // this lane-column's q-row

  // Q as B-operand fragments: B[n=lr][k=quad*8+j], loaded once from global
  bf16x8 b_q[2];
  {
    const long rowoff = base + (long)qi * 3072 + h * 64;
    b_q[0] = *(const bf16x8*)(qkv + rowoff + quad * 8);
    b_q[1] = *(const bf16x8*)(qkv + rowoff + 32 + quad * 8);
  }

  const float NEGS = -30000.f;  // inf-free mask (exp underflows to 0)
  float m_i = NEGS, l_i = 0.f;
  f32x4 o_acc[4];
#pragma unroll
  for (int dt = 0; dt < 4; ++dt) o_acc[dt] = (f32x4){0.f, 0.f, 0.f, 0.f};

  for (int kv0 = 0; kv0 < q0 + 64; kv0 += 64) {
    __syncthreads();  // Ks/Vt reuse guard
    // stage K rows (vectorized, coalesced)
#pragma unroll
    for (int c = 0; c < 2; ++c) {
      const int e = tid * 8 + c * 2048;
      const int r = e >> 6, col = e & 63;
      *(bf16x8*)&Ks[r * 72 + col] =
          *(const bf16x8*)(qkv + base + (long)(kv0 + r) * 3072 + 1024 + h * 64 + col);
    }
    // stage V transposed: vector global load + scatter LDS writes
#pragma unroll
    for (int c = 0; c < 2; ++c) {
      const int e = tid * 8 + c * 2048;
      const int r = e >> 6, col = e & 63;
      bf16x8 v = *(const bf16x8*)(qkv + base + (long)(kv0 + r) * 3072 + 2048 + h * 64 + col);
#pragma unroll
      for (int j = 0; j < 8; ++j) Vt[(col + j) * 72 + r] = v[j];
    }
    __syncthreads();

    // wave-uniform skip: this wave's rows all < kv0 -> tile fully masked
    if (kv0 > q0 + wave * 16 + 15) continue;

    // S^T = K * Q^T : st[kt] D-layout: row=kv(quad*4+r), col=q(lr)
    f32x4 st[4];
#pragma unroll
    for (int kt = 0; kt < 4; ++kt) st[kt] = (f32x4){0.f, 0.f, 0.f, 0.f};
#pragma unroll
    for (int ks = 0; ks < 2; ++ks) {
      bf16x8 ak[4];
#pragma unroll
      for (int kt = 0; kt < 4; ++kt)
        ak[kt] = *(const bf16x8*)&Ks[(kt * 16 + lr) * 72 + ks * 32 + quad * 8];
#pragma unroll
      for (int kt = 0; kt < 4; ++kt) st[kt] = MFMA16(ak[kt], b_q[ks], st[kt]);
    }

    // scale + causal mask (wave-uniform fast path when fully unmasked)
    if (kv0 + 64 <= q0 + wave * 16) {
#pragma unroll
      for (int kt = 0; kt < 4; ++kt)
#pragma unroll
        for (int r = 0; r < 4; ++r) st[kt][r] *= 0.125f;
    } else {
#pragma unroll
      for (int kt = 0; kt < 4; ++kt) {
        const int d0 = kv0 + kt * 16 + quad * 4 - qi;
#pragma unroll
        for (int r = 0; r < 4; ++r)
          st[kt][r] = (d0 + r <= 0) ? st[kt][r] * 0.125f : NEGS;
      }
    }

    // online softmax: 15 in-lane max + 2 shfl (vs 8 shfl/row before)
    float mx = st[0][0];
#pragma unroll
    for (int kt = 0; kt < 4; ++kt)
#pragma unroll
      for (int r = 0; r < 4; ++r) mx = fmaxf(mx, st[kt][r]);
    mx = fmaxf(mx, __shfl_xor(mx, 16));
    mx = fmaxf(mx, __shfl_xor(mx, 32));
    const float mnew = fmaxf(m_i, mx);
    const float alpha = __expf(m_i - mnew);
    float rs = 0.f;
#pragma unroll
    for (int kt = 0; kt < 4; ++kt)
#pragma unroll
      for (int r = 0; r < 4; ++r) {
        const float p = __expf(st[kt][r] - mnew);
        st[kt][r] = p;
        rs += p;
      }
    rs += __shfl_xor(rs, 16);
    rs += __shfl_xor(rs, 32);
    l_i = l_i * alpha + rs;
    m_i = mnew;

    // P -> wave-private LDS, row-major [q=lr][kv]
#pragma unroll
    for (int kt = 0; kt < 4; ++kt)
#pragma unroll
      for (int r = 0; r < 4; ++r)
        pqw[lr * 72 + kt * 16 + quad * 4 + r] = (__bf16)st[kt][r];

#pragma unroll
    for (int dt = 0; dt < 4; ++dt)
#pragma unroll
      for (int r = 0; r < 4; ++r) o_acc[dt][r] *= alpha;

    // wave-private Pq: lgkmcnt(0)+compiler fence suffices, no barrier
    __threadfence_block();

    // O^T tile: o_acc[dt] D-layout row=d(quad*4+r), col=q(lr); A=V^T, B=P
#pragma unroll
    for (int ks = 0; ks < 2; ++ks) {
      bf16x8 bp = *(const bf16x8*)&pqw[lr * 72 + ks * 32 + quad * 8];
#pragma unroll
      for (int dt = 0; dt < 4; ++dt) {
        bf16x8 av = *(const bf16x8*)&Vt[(dt * 16 + lr) * 72 + ks * 32 + quad * 8];
        o_acc[dt] = MFMA16(av, bp, o_acc[dt]);
      }
    }
  }

  // epilogue: O/l -> q-slice in place; 4x 8B vector stores per lane
  const float inv = 1.f / fmaxf(l_i, 1e-30f);
  const long obase = base + (long)qi * 3072 + h * 64 + quad * 4;
#pragma unroll
  for (int dt = 0; dt < 4; ++dt) {
    bf16x4 ov;
#pragma unroll
    for (int r = 0; r < 4; ++r) ov[r] = (__bf16)(o_acc[dt][r] * inv);
    *(bf16x4*)(qkv + obase + dt * 16) = ov;
  }
}

extern "C" void kernel_launch(void* const* d_in, const int* in_sizes, int n_in,
                              void* d_out, int out_size, void* d_ws, size_t ws_size,
                              hipStream_t stream) {
  const float* x = (const float*)d_in[0];
  const float* w_qkv = (const float*)d_in[1];
  const float* w_o = (const float*)d_in[2];
  for (int i = 0; i < n_in; ++i) {
    if (in_sizes[i] == MTOT * DM) x = (const float*)d_in[i];
    else if (in_sizes[i] == 3 * DM * DM) w_qkv = (const float*)d_in[i];
    else if (in_sizes[i] == DM * DM) w_o = (const float*)d_in[i];
  }
  float* out = (float*)d_out;  // FP32 output per reference dtype

  const size_t qkvBytes = (size_t)MTOT * 3072 * 2;  // 24 MiB
  if (ws_size < qkvBytes) {
    sentinel_fill<<<256, 256, 0, stream>>>(out, out_size);
    return;
  }

  __bf16* qkv = (__bf16*)d_ws;

  gemm_nt<1, 1, __bf16><<<dim3(3072 / 128, MTOT / 128), 256, 0, stream>>>(
      x, w_qkv, qkv, MTOT, 3072, DM, DM, 1e4f);
  attn_fwd<<<dim3(SEQ / 64, NH, BATCH), 256, 0, stream>>>(qkv);
  gemm_nt<0, 1, float><<<dim3(DM / 128, MTOT / 128), 256, 0, stream>>>(
      qkv, w_o, out, MTOT, DM, DM, 3072, 2e4f);
}

// Round 10
// 234.215 us; speedup vs baseline: 1.4717x; 1.1684x over previous
//
#include <hip/hip_runtime.h>

constexpr int SEQ = 2048;
constexpr int DM = 1024;
constexpr int NH = 16;
constexpr int BATCH = 2;
constexpr int MTOT = BATCH * SEQ;   // 4096

typedef __bf16 bf16x8 __attribute__((ext_vector_type(8)));
typedef __bf16 bf16x4 __attribute__((ext_vector_type(4)));
typedef float f32x4 __attribute__((ext_vector_type(4)));

#define MFMA16(a, b, c) __builtin_amdgcn_mfma_f32_16x16x32_bf16((a), (b), (c), 0, 0, 0)

__device__ __forceinline__ void async_copy16(const void* g, void* l) {
  __builtin_amdgcn_global_load_lds((const __attribute__((address_space(1))) void*)g,
                                   (__attribute__((address_space(3))) void*)l, 16, 0, 0);
}

__global__ void sentinel_fill(float* out, int n) {
  int i = blockIdx.x * blockDim.x + threadIdx.x;
  for (; i < n; i += gridDim.x * blockDim.x) out[i] = 0.25f;
}

// one-shot fp32 -> bf16 conversion of x, w_qkv, w_o (block-aligned ranges)
__global__ __launch_bounds__(256) void cvt_all(const float* __restrict__ x,
                                               const float* __restrict__ wq,
                                               const float* __restrict__ wo,
                                               __bf16* __restrict__ xb,
                                               __bf16* __restrict__ wqb,
                                               __bf16* __restrict__ wob) {
  const long i = (long)(blockIdx.x * 256 + threadIdx.x) * 8;
  const float* src;
  __bf16* dst;
  long off;
  if (i < 4194304) { src = x; dst = xb; off = i; }
  else if (i < 7340032) { src = wq; dst = wqb; off = i - 4194304; }
  else { src = wo; dst = wob; off = i - 7340032; }
  f32x4 lo = *(const f32x4*)(src + off);
  f32x4 hi = *(const f32x4*)(src + off + 4);
  bf16x8 r;
#pragma unroll
  for (int j = 0; j < 4; ++j) { r[j] = (__bf16)lo[j]; r[4 + j] = (__bf16)hi[j]; }
  *(bf16x8*)(dst + off) = r;
}

// FAST GEMM: C[M,N] = A[M,K]*B[N,K]^T, bf16 in, m97 structure:
// 128x128 tile, BK=32, global_load_lds width 16 (wave-uniform LDS base).
template <typename OutT>
__global__ __launch_bounds__(256) void gemm_bt(const __bf16* __restrict__ A,
                                               const __bf16* __restrict__ B,
                                               OutT* __restrict__ C,
                                               int M, int N, int K, int lda,
                                               float nanSig) {
  __shared__ alignas(16) __bf16 As[128 * 32];
  __shared__ alignas(16) __bf16 Bs[128 * 32];
  const int tid = threadIdx.x;
  const int lane = tid & 63;
  const int wave = tid >> 6;
  const int lr = lane & 15;
  const int quad = lane >> 4;
  const int wm = (wave >> 1) * 64;
  const int wn = (wave & 1) * 64;
  const int m0 = blockIdx.y * 128;
  const int n0 = blockIdx.x * 128;

  const int ra = tid >> 2;            // 0..63
  const int ca = (tid & 3) * 8;       // 0,8,16,24
  const __bf16* gA0 = A + (long)(m0 + ra) * lda + ca;
  const __bf16* gA1 = A + (long)(m0 + 64 + ra) * lda + ca;
  const __bf16* gB0 = B + (long)(n0 + ra) * K + ca;
  const __bf16* gB1 = B + (long)(n0 + 64 + ra) * K + ca;
  __bf16* lA0 = &As[wave * 512];          // wave-uniform; HW adds lane*16B
  __bf16* lA1 = &As[2048 + wave * 512];
  __bf16* lB0 = &Bs[wave * 512];
  __bf16* lB1 = &Bs[2048 + wave * 512];

  f32x4 acc[4][4];
#pragma unroll
  for (int i = 0; i < 4; ++i)
#pragma unroll
    for (int j = 0; j < 4; ++j) acc[i][j] = (f32x4){0.f, 0.f, 0.f, 0.f};

  for (int k0 = 0; k0 < K; k0 += 32) {
    async_copy16(gA0 + k0, lA0);
    async_copy16(gA1 + k0, lA1);
    async_copy16(gB0 + k0, lB0);
    async_copy16(gB1 + k0, lB1);
    __builtin_amdgcn_s_waitcnt(0);
    __syncthreads();
    bf16x8 af[4], bfr[4];
#pragma unroll
    for (int i = 0; i < 4; ++i) af[i] = *(const bf16x8*)&As[(wm + i * 16 + lr) * 32 + quad * 8];
#pragma unroll
    for (int j = 0; j < 4; ++j) bfr[j] = *(const bf16x8*)&Bs[(wn + j * 16 + lr) * 32 + quad * 8];
#pragma unroll
    for (int i = 0; i < 4; ++i)
#pragma unroll
      for (int j = 0; j < 4; ++j) acc[i][j] = MFMA16(af[i], bfr[j], acc[i][j]);
    __syncthreads();
  }

#pragma unroll
  for (int i = 0; i < 4; ++i) {
    const int row = m0 + wm + i * 16 + quad * 4;
#pragma unroll
    for (int j = 0; j < 4; ++j) {
      const int col = n0 + wn + j * 16 + lr;
#pragma unroll
      for (int r = 0; r < 4; ++r) {
        float v = acc[i][j][r];
        if (!(v == v)) v = nanSig;
        C[(long)(row + r) * N + col] = (OutT)v;
      }
    }
  }
}

// SLOW GEMM (fallback when ws can't hold converted weights): R9's verified
// manual-staging kernel with inline fp32->bf16 conversion.
template <int F32>
__device__ __forceinline__ bf16x8 load_cvt8(const void* base, long off) {
  if constexpr (F32) {
    const float* p = (const float*)base + off;
    f32x4 lo = *(const f32x4*)p;
    f32x4 hi = *(const f32x4*)(p + 4);
    bf16x8 r;
#pragma unroll
    for (int j = 0; j < 4; ++j) { r[j] = (__bf16)lo[j]; r[4 + j] = (__bf16)hi[j]; }
    return r;
  } else {
    return *(const bf16x8*)((const __bf16*)base + off);
  }
}

template <int AF32, int BF32, typename OutT>
__global__ __launch_bounds__(256) void gemm_nt(const void* __restrict__ Av,
                                               const void* __restrict__ Bv,
                                               OutT* __restrict__ C,
                                               int M, int N, int K, int lda,
                                               float nanSig) {
  __shared__ alignas(16) __bf16 As[128 * 32];
  __shared__ alignas(16) __bf16 Bs[128 * 32];
  const int tid = threadIdx.x;
  const int lane = tid & 63;
  const int wave = tid >> 6;
  const int lr = lane & 15;
  const int quad = lane >> 4;
  const int wm = (wave >> 1) * 64;
  const int wn = (wave & 1) * 64;
  const int m0 = blockIdx.y * 128;
  const int n0 = blockIdx.x * 128;

  const int r0 = tid >> 2;
  const int r1 = 64 + (tid >> 2);
  const int cc = (tid & 3) * 8;
  const long aBase0 = (long)(m0 + r0) * lda + cc;
  const long aBase1 = (long)(m0 + r1) * lda + cc;
  const long bBase0 = (long)(n0 + r0) * K + cc;
  const long bBase1 = (long)(n0 + r1) * K + cc;
  __bf16* lA0 = &As[r0 * 32 + cc];
  __bf16* lA1 = &As[r1 * 32 + cc];
  __bf16* lB0 = &Bs[r0 * 32 + cc];
  __bf16* lB1 = &Bs[r1 * 32 + cc];

  f32x4 acc[4][4];
#pragma unroll
  for (int i = 0; i < 4; ++i)
#pragma unroll
    for (int j = 0; j < 4; ++j) acc[i][j] = (f32x4){0.f, 0.f, 0.f, 0.f};

  for (int k0 = 0; k0 < K; k0 += 32) {
    bf16x8 va0 = load_cvt8<AF32>(Av, aBase0 + k0);
    bf16x8 va1 = load_cvt8<AF32>(Av, aBase1 + k0);
    bf16x8 vb0 = load_cvt8<BF32>(Bv, bBase0 + k0);
    bf16x8 vb1 = load_cvt8<BF32>(Bv, bBase1 + k0);
    __syncthreads();
    *(bf16x8*)lA0 = va0;
    *(bf16x8*)lA1 = va1;
    *(bf16x8*)lB0 = vb0;
    *(bf16x8*)lB1 = vb1;
    __syncthreads();
    bf16x8 af[4], bfr[4];
#pragma unroll
    for (int i = 0; i < 4; ++i) af[i] = *(const bf16x8*)&As[(wm + i * 16 + lr) * 32 + quad * 8];
#pragma unroll
    for (int j = 0; j < 4; ++j) bfr[j] = *(const bf16x8*)&Bs[(wn + j * 16 + lr) * 32 + quad * 8];
#pragma unroll
    for (int i = 0; i < 4; ++i)
#pragma unroll
      for (int j = 0; j < 4; ++j) acc[i][j] = MFMA16(af[i], bfr[j], acc[i][j]);
  }

#pragma unroll
  for (int i = 0; i < 4; ++i) {
    const int row = m0 + wm + i * 16 + quad * 4;
#pragma unroll
    for (int j = 0; j < 4; ++j) {
      const int col = n0 + wn + j * 16 + lr;
#pragma unroll
      for (int r = 0; r < 4; ++r) {
        float v = acc[i][j][r];
        if (!(v == v)) v = nanSig;
        C[(long)(row + r) * N + col] = (OutT)v;
      }
    }
  }
}

// Flash causal attention, S^T formulation, q-tile 128 (wave owns 2x16 q-rows),
// KV tile 64. In-place output into the q-slice of qkv.
__global__ __launch_bounds__(256, 2) void attn_fwd(__bf16* __restrict__ qkv) {
  const int qt = gridDim.x - 1 - blockIdx.x;  // big workloads first
  const int h = blockIdx.y;
  const int b = blockIdx.z;
  const int q0 = qt * 128;
  const int tid = threadIdx.x;
  const int lane = tid & 63;
  const int wave = tid >> 6;
  const int lr = lane & 15;
  const int quad = lane >> 4;

  __shared__ alignas(16) __bf16 Ks[64 * 72];   // K rows [kv][d]
  __shared__ alignas(16) __bf16 Vt[64 * 72];   // V^T [d][kv]
  __shared__ alignas(16) __bf16 Pq[128 * 72];  // per-wave P [q][kv]

  __bf16* pqw = &Pq[wave * 32 * 72];
  const long base = (long)b * SEQ * 3072;
  const int qrow0 = q0 + wave * 32;
  int qi[2] = {qrow0 + lr, qrow0 + 16 + lr};

  bf16x8 b_q[2][2];
#pragma unroll
  for (int qg = 0; qg < 2; ++qg) {
    const long rowoff = base + (long)qi[qg] * 3072 + h * 64;
    b_q[qg][0] = *(const bf16x8*)(qkv + rowoff + quad * 8);
    b_q[qg][1] = *(const bf16x8*)(qkv + rowoff + 32 + quad * 8);
  }

  const float NEGS = -30000.f;
  float m_i[2] = {NEGS, NEGS}, l_i[2] = {0.f, 0.f};
  f32x4 o_acc[2][4];
#pragma unroll
  for (int qg = 0; qg < 2; ++qg)
#pragma unroll
    for (int dt = 0; dt < 4; ++dt) o_acc[qg][dt] = (f32x4){0.f, 0.f, 0.f, 0.f};

  const bool oddr = (tid >> 3) & 1;
  const int jb = oddr ? 4 : 0;

  for (int kv0 = 0; kv0 < q0 + 128; kv0 += 64) {
    __syncthreads();  // Ks/Vt reuse guard
    // K rows, b128 writes (conflict-free-ish)
#pragma unroll
    for (int c = 0; c < 2; ++c) {
      const int e = tid * 8 + c * 2048;
      const int r = e >> 6, col = e & 63;
      *(bf16x8*)&Ks[r * 72 + col] =
          *(const bf16x8*)(qkv + base + (long)(kv0 + r) * 3072 + 1024 + h * 64 + col);
    }
    // V^T via pair-transpose: shfl_xor(8) pairs rows (r, r+1), b32 writes
    // (R9's 16x b16 scatter was 16-way bank-conflicted: 2.1e7 conflict cycles)
#pragma unroll
    for (int c = 0; c < 2; ++c) {
      const int e = tid * 8 + c * 2048;
      const int r = e >> 6, col = e & 63;
      bf16x8 v = *(const bf16x8*)(qkv + base + (long)(kv0 + r) * 3072 + 2048 + h * 64 + col);
      int vd[4], od[4];
      __builtin_memcpy(vd, &v, 16);
#pragma unroll
      for (int i = 0; i < 4; ++i) od[i] = __shfl_xor(vd[i], 8);
      const int rr = r & ~1;
#pragma unroll
      for (int i = 0; i < 4; ++i) {
        const int j = jb + i;
        const int a = vd[j >> 1], bb = od[j >> 1];
        const int lo = oddr ? bb : a;
        const int hi = oddr ? a : bb;
        const int pair = (j & 1) ? (int)(((unsigned)lo >> 16) | (hi & 0xffff0000))
                                 : (int)((lo & 0xffff) | (hi << 16));
        *(int*)&Vt[(col + j) * 72 + rr] = pair;
      }
    }
    __syncthreads();

    if (kv0 > qrow0 + 31) continue;  // wave fully masked

    // S^T = K * Q^T ; st[qg][kt]: row=kv(quad*4+r), col=q(lr)
    f32x4 st[2][4];
#pragma unroll
    for (int qg = 0; qg < 2; ++qg)
#pragma unroll
      for (int kt = 0; kt < 4; ++kt) st[qg][kt] = (f32x4){0.f, 0.f, 0.f, 0.f};
#pragma unroll
    for (int ks = 0; ks < 2; ++ks) {
      bf16x8 ak[4];
#pragma unroll
      for (int kt = 0; kt < 4; ++kt)
        ak[kt] = *(const bf16x8*)&Ks[(kt * 16 + lr) * 72 + ks * 32 + quad * 8];
#pragma unroll
      for (int qg = 0; qg < 2; ++qg)
#pragma unroll
        for (int kt = 0; kt < 4; ++kt)
          st[qg][kt] = MFMA16(ak[kt], b_q[qg][ks], st[qg][kt]);
    }

#pragma unroll
    for (int qg = 0; qg < 2; ++qg) {
      // scale + causal mask
      if (kv0 + 64 <= qrow0 + qg * 16) {
#pragma unroll
        for (int kt = 0; kt < 4; ++kt)
#pragma unroll
          for (int r = 0; r < 4; ++r) st[qg][kt][r] *= 0.125f;
      } else {
#pragma unroll
        for (int kt = 0; kt < 4; ++kt) {
          const int d0 = kv0 + kt * 16 + quad * 4 - qi[qg];
#pragma unroll
          for (int r = 0; r < 4; ++r)
            st[qg][kt][r] = (d0 + r <= 0) ? st[qg][kt][r] * 0.125f : NEGS;
        }
      }
      // online softmax: in-lane over 16 kv + 2 shfl
      float mx = st[qg][0][0];
#pragma unroll
      for (int kt = 0; kt < 4; ++kt)
#pragma unroll
        for (int r = 0; r < 4; ++r) mx = fmaxf(mx, st[qg][kt][r]);
      mx = fmaxf(mx, __shfl_xor(mx, 16));
      mx = fmaxf(mx, __shfl_xor(mx, 32));
      const float mnew = fmaxf(m_i[qg], mx);
      const float alpha = __expf(m_i[qg] - mnew);
      float rs = 0.f;
#pragma unroll
      for (int kt = 0; kt < 4; ++kt)
#pragma unroll
        for (int r = 0; r < 4; ++r) {
          const float p = __expf(st[qg][kt][r] - mnew);
          st[qg][kt][r] = p;
          rs += p;
        }
      rs += __shfl_xor(rs, 16);
      rs += __shfl_xor(rs, 32);
      l_i[qg] = l_i[qg] * alpha + rs;
      m_i[qg] = mnew;
      // P -> wave-private LDS rows, vectorized b64 writes (2-way = free)
#pragma unroll
      for (int kt = 0; kt < 4; ++kt) {
        bf16x4 pv;
#pragma unroll
        for (int r = 0; r < 4; ++r) pv[r] = (__bf16)st[qg][kt][r];
        *(bf16x4*)&pqw[(qg * 16 + lr) * 72 + kt * 16 + quad * 4] = pv;
      }
#pragma unroll
      for (int dt = 0; dt < 4; ++dt)
#pragma unroll
        for (int r = 0; r < 4; ++r) o_acc[qg][dt][r] *= alpha;
    }

    __threadfence_block();  // wave-private Pq write->read ordering

    // O^T += V^T * P^T
#pragma unroll
    for (int ks = 0; ks < 2; ++ks) {
      bf16x8 av[4];
#pragma unroll
      for (int dt = 0; dt < 4; ++dt)
        av[dt] = *(const bf16x8*)&Vt[(dt * 16 + lr) * 72 + ks * 32 + quad * 8];
#pragma unroll
      for (int qg = 0; qg < 2; ++qg) {
        bf16x8 bp = *(const bf16x8*)&pqw[(qg * 16 + lr) * 72 + ks * 32 + quad * 8];
#pragma unroll
        for (int dt = 0; dt < 4; ++dt) o_acc[qg][dt] = MFMA16(av[dt], bp, o_acc[qg][dt]);
      }
    }
  }

  // epilogue: O/l -> q-slice in place
#pragma unroll
  for (int qg = 0; qg < 2; ++qg) {
    const float inv = 1.f / fmaxf(l_i[qg], 1e-30f);
    const long obase = base + (long)qi[qg] * 3072 + h * 64 + quad * 4;
#pragma unroll
    for (int dt = 0; dt < 4; ++dt) {
      bf16x4 ov;
#pragma unroll
      for (int r = 0; r < 4; ++r) ov[r] = (__bf16)(o_acc[qg][dt][r] * inv);
      *(bf16x4*)(qkv + obase + dt * 16) = ov;
    }
  }
}

extern "C" void kernel_launch(void* const* d_in, const int* in_sizes, int n_in,
                              void* d_out, int out_size, void* d_ws, size_t ws_size,
                              hipStream_t stream) {
  const float* x = (const float*)d_in[0];
  const float* w_qkv = (const float*)d_in[1];
  const float* w_o = (const float*)d_in[2];
  for (int i = 0; i < n_in; ++i) {
    if (in_sizes[i] == MTOT * DM) x = (const float*)d_in[i];
    else if (in_sizes[i] == 3 * DM * DM) w_qkv = (const float*)d_in[i];
    else if (in_sizes[i] == DM * DM) w_o = (const float*)d_in[i];
  }
  float* out = (float*)d_out;  // FP32 output per reference dtype

  const size_t qkvBytes = (size_t)MTOT * 3072 * 2;       // 24 MiB
  const size_t xbBytes = (size_t)MTOT * DM * 2;          // 8 MiB
  const size_t wqBytes = (size_t)3 * DM * DM * 2;        // 6 MiB
  const size_t woBytes = (size_t)DM * DM * 2;            // 2 MiB
  const size_t needFast = qkvBytes + xbBytes + wqBytes + woBytes;  // 40 MiB

  __bf16* qkv = (__bf16*)d_ws;

  if (ws_size >= needFast) {
    // FAST: pre-convert to bf16, then m97 async GEMMs
    __bf16* xb = (__bf16*)((char*)d_ws + qkvBytes);
    __bf16* wqb = (__bf16*)((char*)d_ws + qkvBytes + xbBytes);
    __bf16* wob = (__bf16*)((char*)d_ws + qkvBytes + xbBytes + wqBytes);
    cvt_all<<<4096, 256, 0, stream>>>(x, w_qkv, w_o, xb, wqb, wob);
    gemm_bt<__bf16><<<dim3(3072 / 128, MTOT / 128), 256, 0, stream>>>(
        xb, wqb, qkv, MTOT, 3072, DM, DM, 1e4f);
    attn_fwd<<<dim3(SEQ / 128, NH, BATCH), 256, 0, stream>>>(qkv);
    gemm_bt<float><<<dim3(DM / 128, MTOT / 128), 256, 0, stream>>>(
        qkv, wob, out, MTOT, DM, DM, 3072, 2e4f);
  } else if (ws_size >= qkvBytes) {
    // SLOW fallback: R9's verified manual-cvt GEMMs
    gemm_nt<1, 1, __bf16><<<dim3(3072 / 128, MTOT / 128), 256, 0, stream>>>(
        x, w_qkv, qkv, MTOT, 3072, DM, DM, 1e4f);
    attn_fwd<<<dim3(SEQ / 128, NH, BATCH), 256, 0, stream>>>(qkv);
    gemm_nt<0, 1, float><<<dim3(DM / 128, MTOT / 128), 256, 0, stream>>>(
        qkv, w_o, out, MTOT, DM, DM, 3072, 2e4f);
  } else {
    sentinel_fill<<<256, 256, 0, stream>>>(out, out_size);
  }
}

// Round 11
// 233.771 us; speedup vs baseline: 1.4745x; 1.0019x over previous
//
#include <hip/hip_runtime.h>

constexpr int SEQ = 2048;
constexpr int DM = 1024;
constexpr int NH = 16;
constexpr int BATCH = 2;
constexpr int MTOT = BATCH * SEQ;   // 4096

typedef __bf16 bf16x8 __attribute__((ext_vector_type(8)));
typedef __bf16 bf16x4 __attribute__((ext_vector_type(4)));
typedef float f32x4 __attribute__((ext_vector_type(4)));

#define MFMA16(a, b, c) __builtin_amdgcn_mfma_f32_16x16x32_bf16((a), (b), (c), 0, 0, 0)

__device__ __forceinline__ void async_copy16(const void* g, void* l) {
  __builtin_amdgcn_global_load_lds((const __attribute__((address_space(1))) void*)g,
                                   (__attribute__((address_space(3))) void*)l, 16, 0, 0);
}

__global__ void sentinel_fill(float* out, int n) {
  int i = blockIdx.x * blockDim.x + threadIdx.x;
  for (; i < n; i += gridDim.x * blockDim.x) out[i] = 0.25f;
}

// one-shot fp32 -> bf16 conversion of x, w_qkv, w_o
__global__ __launch_bounds__(256) void cvt_all(const float* __restrict__ x,
                                               const float* __restrict__ wq,
                                               const float* __restrict__ wo,
                                               __bf16* __restrict__ xb,
                                               __bf16* __restrict__ wqb,
                                               __bf16* __restrict__ wob) {
  const long i = (long)(blockIdx.x * 256 + threadIdx.x) * 8;
  const float* src;
  __bf16* dst;
  long off;
  if (i < 4194304) { src = x; dst = xb; off = i; }
  else if (i < 7340032) { src = wq; dst = wqb; off = i - 4194304; }
  else { src = wo; dst = wob; off = i - 7340032; }
  f32x4 lo = *(const f32x4*)(src + off);
  f32x4 hi = *(const f32x4*)(src + off + 4);
  bf16x8 r;
#pragma unroll
  for (int j = 0; j < 4; ++j) { r[j] = (__bf16)lo[j]; r[4 + j] = (__bf16)hi[j]; }
  *(bf16x8*)(dst + off) = r;
}

// FAST GEMM: C[M,N]=A[M,K]*B[N,K]^T, bf16 in, m97 structure (verified R10).
template <typename OutT>
__global__ __launch_bounds__(256) void gemm_bt(const __bf16* __restrict__ A,
                                               const __bf16* __restrict__ B,
                                               OutT* __restrict__ C,
                                               int M, int N, int K, int lda,
                                               float nanSig) {
  __shared__ alignas(16) __bf16 As[128 * 32];
  __shared__ alignas(16) __bf16 Bs[128 * 32];
  const int tid = threadIdx.x;
  const int lane = tid & 63;
  const int wave = tid >> 6;
  const int lr = lane & 15;
  const int quad = lane >> 4;
  const int wm = (wave >> 1) * 64;
  const int wn = (wave & 1) * 64;
  const int m0 = blockIdx.y * 128;
  const int n0 = blockIdx.x * 128;

  const int ra = tid >> 2;
  const int ca = (tid & 3) * 8;
  const __bf16* gA0 = A + (long)(m0 + ra) * lda + ca;
  const __bf16* gA1 = A + (long)(m0 + 64 + ra) * lda + ca;
  const __bf16* gB0 = B + (long)(n0 + ra) * K + ca;
  const __bf16* gB1 = B + (long)(n0 + 64 + ra) * K + ca;
  __bf16* lA0 = &As[wave * 512];
  __bf16* lA1 = &As[2048 + wave * 512];
  __bf16* lB0 = &Bs[wave * 512];
  __bf16* lB1 = &Bs[2048 + wave * 512];

  f32x4 acc[4][4];
#pragma unroll
  for (int i = 0; i < 4; ++i)
#pragma unroll
    for (int j = 0; j < 4; ++j) acc[i][j] = (f32x4){0.f, 0.f, 0.f, 0.f};

  for (int k0 = 0; k0 < K; k0 += 32) {
    async_copy16(gA0 + k0, lA0);
    async_copy16(gA1 + k0, lA1);
    async_copy16(gB0 + k0, lB0);
    async_copy16(gB1 + k0, lB1);
    __builtin_amdgcn_s_waitcnt(0);
    __syncthreads();
    bf16x8 af[4], bfr[4];
#pragma unroll
    for (int i = 0; i < 4; ++i) af[i] = *(const bf16x8*)&As[(wm + i * 16 + lr) * 32 + quad * 8];
#pragma unroll
    for (int j = 0; j < 4; ++j) bfr[j] = *(const bf16x8*)&Bs[(wn + j * 16 + lr) * 32 + quad * 8];
#pragma unroll
    for (int i = 0; i < 4; ++i)
#pragma unroll
      for (int j = 0; j < 4; ++j) acc[i][j] = MFMA16(af[i], bfr[j], acc[i][j]);
    __syncthreads();
  }

#pragma unroll
  for (int i = 0; i < 4; ++i) {
    const int row = m0 + wm + i * 16 + quad * 4;
#pragma unroll
    for (int j = 0; j < 4; ++j) {
      const int col = n0 + wn + j * 16 + lr;
#pragma unroll
      for (int r = 0; r < 4; ++r) {
        float v = acc[i][j][r];
        if (!(v == v)) v = nanSig;
        C[(long)(row + r) * N + col] = (OutT)v;
      }
    }
  }
}

// SLOW fallback GEMM (inline fp32 cvt, verified R9).
template <int F32>
__device__ __forceinline__ bf16x8 load_cvt8(const void* base, long off) {
  if constexpr (F32) {
    const float* p = (const float*)base + off;
    f32x4 lo = *(const f32x4*)p;
    f32x4 hi = *(const f32x4*)(p + 4);
    bf16x8 r;
#pragma unroll
    for (int j = 0; j < 4; ++j) { r[j] = (__bf16)lo[j]; r[4 + j] = (__bf16)hi[j]; }
    return r;
  } else {
    return *(const bf16x8*)((const __bf16*)base + off);
  }
}

template <int AF32, int BF32, typename OutT>
__global__ __launch_bounds__(256) void gemm_nt(const void* __restrict__ Av,
                                               const void* __restrict__ Bv,
                                               OutT* __restrict__ C,
                                               int M, int N, int K, int lda,
                                               float nanSig) {
  __shared__ alignas(16) __bf16 As[128 * 32];
  __shared__ alignas(16) __bf16 Bs[128 * 32];
  const int tid = threadIdx.x;
  const int lane = tid & 63;
  const int wave = tid >> 6;
  const int lr = lane & 15;
  const int quad = lane >> 4;
  const int wm = (wave >> 1) * 64;
  const int wn = (wave & 1) * 64;
  const int m0 = blockIdx.y * 128;
  const int n0 = blockIdx.x * 128;

  const int r0 = tid >> 2;
  const int r1 = 64 + (tid >> 2);
  const int cc = (tid & 3) * 8;
  const long aBase0 = (long)(m0 + r0) * lda + cc;
  const long aBase1 = (long)(m0 + r1) * lda + cc;
  const long bBase0 = (long)(n0 + r0) * K + cc;
  const long bBase1 = (long)(n0 + r1) * K + cc;
  __bf16* lA0 = &As[r0 * 32 + cc];
  __bf16* lA1 = &As[r1 * 32 + cc];
  __bf16* lB0 = &Bs[r0 * 32 + cc];
  __bf16* lB1 = &Bs[r1 * 32 + cc];

  f32x4 acc[4][4];
#pragma unroll
  for (int i = 0; i < 4; ++i)
#pragma unroll
    for (int j = 0; j < 4; ++j) acc[i][j] = (f32x4){0.f, 0.f, 0.f, 0.f};

  for (int k0 = 0; k0 < K; k0 += 32) {
    bf16x8 va0 = load_cvt8<AF32>(Av, aBase0 + k0);
    bf16x8 va1 = load_cvt8<AF32>(Av, aBase1 + k0);
    bf16x8 vb0 = load_cvt8<BF32>(Bv, bBase0 + k0);
    bf16x8 vb1 = load_cvt8<BF32>(Bv, bBase1 + k0);
    __syncthreads();
    *(bf16x8*)lA0 = va0;
    *(bf16x8*)lA1 = va1;
    *(bf16x8*)lB0 = vb0;
    *(bf16x8*)lB1 = vb1;
    __syncthreads();
    bf16x8 af[4], bfr[4];
#pragma unroll
    for (int i = 0; i < 4; ++i) af[i] = *(const bf16x8*)&As[(wm + i * 16 + lr) * 32 + quad * 8];
#pragma unroll
    for (int j = 0; j < 4; ++j) bfr[j] = *(const bf16x8*)&Bs[(wn + j * 16 + lr) * 32 + quad * 8];
#pragma unroll
    for (int i = 0; i < 4; ++i)
#pragma unroll
      for (int j = 0; j < 4; ++j) acc[i][j] = MFMA16(af[i], bfr[j], acc[i][j]);
  }

#pragma unroll
  for (int i = 0; i < 4; ++i) {
    const int row = m0 + wm + i * 16 + quad * 4;
#pragma unroll
    for (int j = 0; j < 4; ++j) {
      const int col = n0 + wn + j * 16 + lr;
#pragma unroll
      for (int r = 0; r < 4; ++r) {
        float v = acc[i][j][r];
        if (!(v == v)) v = nanSig;
        C[(long)(row + r) * N + col] = (OutT)v;
      }
    }
  }
}

// Flash causal attention, S^T form, ZIGZAG-PAIRED q-tiles + reg-dbuf staging.
// Block pi handles q-tiles A=pi and B=31-pi (64 rows each; wave owns 16 rows
// of each). KV loop covers B's range; A participates while in range. Every
// block does exactly 33 compute-units -> uniform load, no tail.
// Vt is XOR-swizzled (kv ^= 8*((d>>3)&3)) to kill the 8-way write conflict.
__global__ __launch_bounds__(256, 2) void attn_fwd(__bf16* __restrict__ qkv) {
  const int pi = blockIdx.x;      // 0..15
  const int h = blockIdx.y;
  const int b = blockIdx.z;
  const int q0A = pi * 64;
  const int q0B = (31 - pi) * 64;
  const int tid = threadIdx.x;
  const int lane = tid & 63;
  const int wave = tid >> 6;
  const int lr = lane & 15;
  const int quad = lane >> 4;
  const int wq = wave * 16;

  __shared__ alignas(16) __bf16 Ks[64 * 72];   // K rows [kv][d]
  __shared__ alignas(16) __bf16 Vt[64 * 72];   // V^T [d][kv^swz]
  __shared__ alignas(16) __bf16 Pq[128 * 72];  // P [wave*32 + qg*16 + q][kv]

  __bf16* pqw = &Pq[wave * 32 * 72];
  const long base = (long)b * SEQ * 3072;
  const int qi[2] = {q0A + wq + lr, q0B + wq + lr};

  // Q as B-operand fragments (loaded once)
  bf16x8 b_q[2][2];
#pragma unroll
  for (int qg = 0; qg < 2; ++qg) {
    const long rowoff = base + (long)qi[qg] * 3072 + h * 64;
    b_q[qg][0] = *(const bf16x8*)(qkv + rowoff + quad * 8);
    b_q[qg][1] = *(const bf16x8*)(qkv + rowoff + 32 + quad * 8);
  }

  const float NEGS = -30000.f;
  const float SC = 0.18033688f;  // 0.125 * log2(e): softmax in exp2 domain
  float m_i[2] = {NEGS, NEGS}, l_i[2] = {0.f, 0.f};
  f32x4 o_acc[2][4];
#pragma unroll
  for (int qg = 0; qg < 2; ++qg)
#pragma unroll
    for (int dt = 0; dt < 4; ++dt) o_acc[qg][dt] = (f32x4){0.f, 0.f, 0.f, 0.f};

  // staging thread geometry
  const int r_ = tid >> 3;            // 0..31
  const int col_ = (tid & 7) * 8;     // 0..56
  const int l8 = tid & 7;
  const int sw = (l8 & 3) << 3;       // Vt swizzle amount for this thread's cols
  const bool oddr = (tid >> 3) & 1;
  const int jb = oddr ? 4 : 0;

  const int T = 32 - pi;              // KV tiles (B's full causal range)

  // prefetch tile 0 into regs
  bf16x8 kreg[2], vreg[2];
  {
    const long ro = base + (long)r_ * 3072 + h * 64 + col_;
    kreg[0] = *(const bf16x8*)(qkv + ro + 1024);
    kreg[1] = *(const bf16x8*)(qkv + ro + (long)32 * 3072 + 1024);
    vreg[0] = *(const bf16x8*)(qkv + ro + 2048);
    vreg[1] = *(const bf16x8*)(qkv + ro + (long)32 * 3072 + 2048);
  }

  for (int t = 0; t < T; ++t) {
    const int kv0 = t * 64;
    __syncthreads();  // all waves done reading Ks/Vt of prior tile
    // K rows -> LDS (b128)
    *(bf16x8*)&Ks[r_ * 72 + col_] = kreg[0];
    *(bf16x8*)&Ks[(r_ + 32) * 72 + col_] = kreg[1];
    // V^T via pair-transpose + swizzle (b32 writes, 2-way banks = free)
#pragma unroll
    for (int c = 0; c < 2; ++c) {
      const int r = r_ + c * 32;
      const int rr = (r & ~1) ^ sw;
      int vd[4], od[4];
      __builtin_memcpy(vd, &vreg[c], 16);
#pragma unroll
      for (int i = 0; i < 4; ++i) od[i] = __shfl_xor(vd[i], 8);
#pragma unroll
      for (int i = 0; i < 4; ++i) {
        const int j = jb + i;
        const int a = vd[j >> 1], bb = od[j >> 1];
        const int lo = oddr ? bb : a;
        const int hi = oddr ? a : bb;
        const int pair = (j & 1) ? (int)(((unsigned)lo >> 16) | (hi & 0xffff0000))
                                 : (int)((lo & 0xffff) | (hi << 16));
        *(int*)&Vt[(col_ + j) * 72 + rr] = pair;
      }
    }
    __syncthreads();

    // prefetch next tile (latency overlaps compute below)
    if (t + 1 < T) {
      const long ro = base + ((long)(t + 1) * 64 + r_) * 3072 + h * 64 + col_;
      kreg[0] = *(const bf16x8*)(qkv + ro + 1024);
      kreg[1] = *(const bf16x8*)(qkv + ro + (long)32 * 3072 + 1024);
      vreg[0] = *(const bf16x8*)(qkv + ro + 2048);
      vreg[1] = *(const bf16x8*)(qkv + ro + (long)32 * 3072 + 2048);
    }

    const bool actA = (kv0 <= q0A + wq + 15);  // wave-uniform

    // S^T = K * Q^T (K-frags shared across both q-groups)
    f32x4 st[2][4];
#pragma unroll
    for (int kt = 0; kt < 4; ++kt) {
      st[1][kt] = (f32x4){0.f, 0.f, 0.f, 0.f};
      st[0][kt] = (f32x4){0.f, 0.f, 0.f, 0.f};
    }
#pragma unroll
    for (int ks = 0; ks < 2; ++ks) {
      bf16x8 ak[4];
#pragma unroll
      for (int kt = 0; kt < 4; ++kt)
        ak[kt] = *(const bf16x8*)&Ks[(kt * 16 + lr) * 72 + ks * 32 + quad * 8];
#pragma unroll
      for (int kt = 0; kt < 4; ++kt) st[1][kt] = MFMA16(ak[kt], b_q[1][ks], st[1][kt]);
      if (actA) {
#pragma unroll
        for (int kt = 0; kt < 4; ++kt) st[0][kt] = MFMA16(ak[kt], b_q[0][ks], st[0][kt]);
      }
    }

#pragma unroll
    for (int qg = 0; qg < 2; ++qg) {
      if (qg == 0 && !actA) continue;
      const int q0X = (qg == 0) ? q0A : q0B;
      // scale (exp2 domain) + causal mask
      if (kv0 + 64 <= q0X + wq) {
#pragma unroll
        for (int kt = 0; kt < 4; ++kt)
#pragma unroll
          for (int r = 0; r < 4; ++r) st[qg][kt][r] *= SC;
      } else {
#pragma unroll
        for (int kt = 0; kt < 4; ++kt) {
          const int d0 = kv0 + kt * 16 + quad * 4 - qi[qg];
#pragma unroll
          for (int r = 0; r < 4; ++r)
            st[qg][kt][r] = (d0 + r <= 0) ? st[qg][kt][r] * SC : NEGS;
        }
      }
      // online softmax (in-lane over 16 kv + 2 shfl)
      float mx = st[qg][0][0];
#pragma unroll
      for (int kt = 0; kt < 4; ++kt)
#pragma unroll
        for (int r = 0; r < 4; ++r) mx = fmaxf(mx, st[qg][kt][r]);
      mx = fmaxf(mx, __shfl_xor(mx, 16));
      mx = fmaxf(mx, __shfl_xor(mx, 32));
      const float mnew = fmaxf(m_i[qg], mx);
      const float alpha = exp2f(m_i[qg] - mnew);
      float rs = 0.f;
#pragma unroll
      for (int kt = 0; kt < 4; ++kt)
#pragma unroll
        for (int r = 0; r < 4; ++r) {
          const float p = exp2f(st[qg][kt][r] - mnew);
          st[qg][kt][r] = p;
          rs += p;
        }
      rs += __shfl_xor(rs, 16);
      rs += __shfl_xor(rs, 32);
      l_i[qg] = l_i[qg] * alpha + rs;
      m_i[qg] = mnew;
      // P -> wave-private LDS (b64 writes, 2-way = free)
#pragma unroll
      for (int kt = 0; kt < 4; ++kt) {
        bf16x4 pv;
#pragma unroll
        for (int r = 0; r < 4; ++r) pv[r] = (__bf16)st[qg][kt][r];
        *(bf16x4*)&pqw[(qg * 16 + lr) * 72 + kt * 16 + quad * 4] = pv;
      }
#pragma unroll
      for (int dt = 0; dt < 4; ++dt)
#pragma unroll
        for (int r = 0; r < 4; ++r) o_acc[qg][dt][r] *= alpha;
    }

    __threadfence_block();  // wave-private Pq write->read ordering

    // O^T += V^T * P^T (V-frags shared; swizzled block addressing)
#pragma unroll
    for (int ks = 0; ks < 2; ++ks) {
      bf16x8 av[4];
#pragma unroll
      for (int dt = 0; dt < 4; ++dt) {
        const int blk = ((ks << 2) + quad) ^ ((2 * dt + (lr >> 3)) & 3);
        av[dt] = *(const bf16x8*)&Vt[(dt * 16 + lr) * 72 + (blk << 3)];
      }
      {
        bf16x8 bp = *(const bf16x8*)&pqw[(16 + lr) * 72 + ks * 32 + quad * 8];
#pragma unroll
        for (int dt = 0; dt < 4; ++dt) o_acc[1][dt] = MFMA16(av[dt], bp, o_acc[1][dt]);
      }
      if (actA) {
        bf16x8 bp = *(const bf16x8*)&pqw[lr * 72 + ks * 32 + quad * 8];
#pragma unroll
        for (int dt = 0; dt < 4; ++dt) o_acc[0][dt] = MFMA16(av[dt], bp, o_acc[0][dt]);
      }
    }
  }

  // epilogue: O/l -> q-slice in place
#pragma unroll
  for (int qg = 0; qg < 2; ++qg) {
    const float inv = 1.f / fmaxf(l_i[qg], 1e-30f);
    const long obase = base + (long)qi[qg] * 3072 + h * 64 + quad * 4;
#pragma unroll
    for (int dt = 0; dt < 4; ++dt) {
      bf16x4 ov;
#pragma unroll
      for (int r = 0; r < 4; ++r) ov[r] = (__bf16)(o_acc[qg][dt][r] * inv);
      *(bf16x4*)(qkv + obase + dt * 16) = ov;
    }
  }
}

extern "C" void kernel_launch(void* const* d_in, const int* in_sizes, int n_in,
                              void* d_out, int out_size, void* d_ws, size_t ws_size,
                              hipStream_t stream) {
  const float* x = (const float*)d_in[0];
  const float* w_qkv = (const float*)d_in[1];
  const float* w_o = (const float*)d_in[2];
  for (int i = 0; i < n_in; ++i) {
    if (in_sizes[i] == MTOT * DM) x = (const float*)d_in[i];
    else if (in_sizes[i] == 3 * DM * DM) w_qkv = (const float*)d_in[i];
    else if (in_sizes[i] == DM * DM) w_o = (const float*)d_in[i];
  }
  float* out = (float*)d_out;  // FP32 output per reference dtype

  const size_t qkvBytes = (size_t)MTOT * 3072 * 2;       // 24 MiB
  const size_t xbBytes = (size_t)MTOT * DM * 2;          // 8 MiB
  const size_t wqBytes = (size_t)3 * DM * DM * 2;        // 6 MiB
  const size_t woBytes = (size_t)DM * DM * 2;            // 2 MiB
  const size_t needFast = qkvBytes + xbBytes + wqBytes + woBytes;  // 40 MiB

  __bf16* qkv = (__bf16*)d_ws;

  if (ws_size >= needFast) {
    __bf16* xb = (__bf16*)((char*)d_ws + qkvBytes);
    __bf16* wqb = (__bf16*)((char*)d_ws + qkvBytes + xbBytes);
    __bf16* wob = (__bf16*)((char*)d_ws + qkvBytes + xbBytes + wqBytes);
    cvt_all<<<4096, 256, 0, stream>>>(x, w_qkv, w_o, xb, wqb, wob);
    gemm_bt<__bf16><<<dim3(3072 / 128, MTOT / 128), 256, 0, stream>>>(
        xb, wqb, qkv, MTOT, 3072, DM, DM, 1e4f);
    attn_fwd<<<dim3(16, NH, BATCH), 256, 0, stream>>>(qkv);
    gemm_bt<float><<<dim3(DM / 128, MTOT / 128), 256, 0, stream>>>(
        qkv, wob, out, MTOT, DM, DM, 3072, 2e4f);
  } else if (ws_size >= qkvBytes) {
    gemm_nt<1, 1, __bf16><<<dim3(3072 / 128, MTOT / 128), 256, 0, stream>>>(
        x, w_qkv, qkv, MTOT, 3072, DM, DM, 1e4f);
    attn_fwd<<<dim3(16, NH, BATCH), 256, 0, stream>>>(qkv);
    gemm_nt<0, 1, float><<<dim3(DM / 128, MTOT / 128), 256, 0, stream>>>(
        qkv, w_o, out, MTOT, DM, DM, 3072, 2e4f);
  } else {
    sentinel_fill<<<256, 256, 0, stream>>>(out, out_size);
  }
}